// Round 16
// baseline (120.146 us; speedup 1.0000x reference)
//
#include <hip/hip_runtime.h>
#include <math.h>

#define IN_DIM 512
#define OUT_DIM 128
#define BM 64
#define BK 64
#define NKT (IN_DIM / BK)  // 8

typedef __attribute__((ext_vector_type(8))) __bf16 bf16x8;
typedef __attribute__((ext_vector_type(2))) __bf16 bf16x2;
typedef __attribute__((ext_vector_type(4))) float f32x4;
typedef __attribute__((ext_vector_type(2))) float f32x2;

// Manual RNE fp32->bf16 (bit ops) — r5-proven codegen for epilogue/prep.
__device__ inline unsigned short f2bf(float f) {
    unsigned u = __float_as_uint(f);
    u += 0x7FFFu + ((u >> 16) & 1u);  // round-to-nearest-even
    return (unsigned short)(u >> 16);
}
__device__ inline unsigned pack2f(float a, float b) {
    return (unsigned)f2bf(a) | ((unsigned)f2bf(b) << 16);
}

// In-register fp32x8 -> bf16x8 via native paired casts, consumed immediately.
__device__ inline bf16x8 cvt8(const f32x4& lo, const f32x4& hi) {
    bf16x2 p0 = {(__bf16)lo.x, (__bf16)lo.y};
    bf16x2 p1 = {(__bf16)lo.z, (__bf16)lo.w};
    bf16x2 p2 = {(__bf16)hi.x, (__bf16)hi.y};
    bf16x2 p3 = {(__bf16)hi.z, (__bf16)hi.w};
    uint4 u = {__builtin_bit_cast(unsigned, p0), __builtin_bit_cast(unsigned, p1),
               __builtin_bit_cast(unsigned, p2), __builtin_bit_cast(unsigned, p3)};
    return __builtin_bit_cast(bf16x8, u);
}

// async global->LDS, 16B per lane (dest = wave-uniform base + lane*16)
__device__ inline void gload_lds16(const void* g, void* l) {
    __builtin_amdgcn_global_load_lds(
        (const __attribute__((address_space(1))) void*)g,
        (__attribute__((address_space(3))) void*)l, 16, 0, 0);
}

// w [512][128] f32 -> wt2 k-interleaved bf16: wt2[(k>>3)*128 + n][k&7]
__global__ void wt2_kernel(const float* __restrict__ w, unsigned short* __restrict__ wt2) {
    int idx = blockIdx.x * 256 + threadIdx.x;  // 65536 total
    int k = idx >> 7;
    int n = idx & 127;
    wt2[(((k >> 3) * 128) + n) * 8 + (k & 7)] = f2bf(w[idx]);
}

// ---------------------------------------------------------------------------
// FUNCTIONAL GEMM — byte-identical to round 15 (current best-equal).
// ---------------------------------------------------------------------------
__global__ __launch_bounds__(256, 4) void gemm_mfma(const float* __restrict__ x,
                                                    const unsigned short* __restrict__ wt2,
                                                    unsigned short* __restrict__ zb,
                                                    int M) {
    __shared__ float sA[2][BM * BK];  // 2 x 16 KB fp32, col-swizzled
    char* const pAb = (char*)sA;

    const int tid  = threadIdx.x;
    const int lane = tid & 63;
    const int wid  = tid >> 6;
    const int wm   = wid >> 1;  // 0..1
    const int wn   = wid & 1;   // 0..1
    const int block_row = blockIdx.x * BM;

    const int fr  = lane & 15;
    const int fk4 = lane >> 4;

    f32x4 acc[2][4];
#pragma unroll
    for (int i = 0; i < 2; ++i)
#pragma unroll
        for (int j = 0; j < 4; ++j) acc[i][j] = (f32x4){0.f, 0.f, 0.f, 0.f};

    const int s_row = lane >> 4;
    const int s_cb  = (lane & 15) * 16;

    const int rowa0 = wm * 32 + fr;
    const int rowa1 = rowa0 + 16;
    const int swz7  = (fr & 7) << 5;

    const unsigned short* pb = wt2 + fk4 * 1024 + (wn * 64 + fr) * 8;

    bf16x8 Ba0, Ba1, Ba2, Ba3;
    bf16x8 Bb0, Bb1, Bb2, Bb3;
    bf16x8 K10, K11, K12, K13;

#define LOADB0(T, R0, R1, R2, R3)                         \
    R0 = *(const bf16x8*)(pb + (T) * 8192 + 0);           \
    R1 = *(const bf16x8*)(pb + (T) * 8192 + 128);         \
    R2 = *(const bf16x8*)(pb + (T) * 8192 + 256);         \
    R3 = *(const bf16x8*)(pb + (T) * 8192 + 384);

#define LOADB1(T)                                         \
    K10 = *(const bf16x8*)(pb + (T) * 8192 + 4096 + 0);   \
    K11 = *(const bf16x8*)(pb + (T) * 8192 + 4096 + 128); \
    K12 = *(const bf16x8*)(pb + (T) * 8192 + 4096 + 256); \
    K13 = *(const bf16x8*)(pb + (T) * 8192 + 4096 + 384);

#define STAGE(T, BUF)                                                            \
    {                                                                            \
        _Pragma("unroll") for (int i = 0; i < 4; ++i) {                          \
            const int rr = (wid * 4 + i) * 4 + s_row;                            \
            int grow = block_row + rr;                                           \
            grow = (grow < M) ? grow : (M - 1);                                  \
            const char* src = (const char*)x + (size_t)grow * 2048 +             \
                              (T) * 256 + (s_cb ^ ((rr & 7) << 5));              \
            gload_lds16(src, pAb + (BUF) * 16384 + (wid * 4 + i) * 1024);        \
        }                                                                        \
    }

#define COMP(BUF, B0, B1, B2, B3)                                                \
    {                                                                            \
        const char* pT = pAb + (BUF) * 16384;                                    \
        {                                                                        \
            const int cb = (fk4 * 32) ^ swz7;                                    \
            f32x4 lo0 = *(const f32x4*)(pT + rowa0 * 256 + cb);                  \
            f32x4 hi0 = *(const f32x4*)(pT + rowa0 * 256 + cb + 16);             \
            f32x4 lo1 = *(const f32x4*)(pT + rowa1 * 256 + cb);                  \
            f32x4 hi1 = *(const f32x4*)(pT + rowa1 * 256 + cb + 16);             \
            bf16x8 af0 = cvt8(lo0, hi0);                                         \
            bf16x8 af1 = cvt8(lo1, hi1);                                         \
            acc[0][0] = __builtin_amdgcn_mfma_f32_16x16x32_bf16(B0, af0, acc[0][0], 0, 0, 0); \
            acc[0][1] = __builtin_amdgcn_mfma_f32_16x16x32_bf16(B1, af0, acc[0][1], 0, 0, 0); \
            acc[0][2] = __builtin_amdgcn_mfma_f32_16x16x32_bf16(B2, af0, acc[0][2], 0, 0, 0); \
            acc[0][3] = __builtin_amdgcn_mfma_f32_16x16x32_bf16(B3, af0, acc[0][3], 0, 0, 0); \
            acc[1][0] = __builtin_amdgcn_mfma_f32_16x16x32_bf16(B0, af1, acc[1][0], 0, 0, 0); \
            acc[1][1] = __builtin_amdgcn_mfma_f32_16x16x32_bf16(B1, af1, acc[1][1], 0, 0, 0); \
            acc[1][2] = __builtin_amdgcn_mfma_f32_16x16x32_bf16(B2, af1, acc[1][2], 0, 0, 0); \
            acc[1][3] = __builtin_amdgcn_mfma_f32_16x16x32_bf16(B3, af1, acc[1][3], 0, 0, 0); \
        }                                                                        \
        {                                                                        \
            const int cb = (128 + fk4 * 32) ^ swz7;                              \
            f32x4 lo0 = *(const f32x4*)(pT + rowa0 * 256 + cb);                  \
            f32x4 hi0 = *(const f32x4*)(pT + rowa0 * 256 + cb + 16);             \
            f32x4 lo1 = *(const f32x4*)(pT + rowa1 * 256 + cb);                  \
            f32x4 hi1 = *(const f32x4*)(pT + rowa1 * 256 + cb + 16);             \
            bf16x8 af0 = cvt8(lo0, hi0);                                         \
            bf16x8 af1 = cvt8(lo1, hi1);                                         \
            acc[0][0] = __builtin_amdgcn_mfma_f32_16x16x32_bf16(K10, af0, acc[0][0], 0, 0, 0); \
            acc[0][1] = __builtin_amdgcn_mfma_f32_16x16x32_bf16(K11, af0, acc[0][1], 0, 0, 0); \
            acc[0][2] = __builtin_amdgcn_mfma_f32_16x16x32_bf16(K12, af0, acc[0][2], 0, 0, 0); \
            acc[0][3] = __builtin_amdgcn_mfma_f32_16x16x32_bf16(K13, af0, acc[0][3], 0, 0, 0); \
            acc[1][0] = __builtin_amdgcn_mfma_f32_16x16x32_bf16(K10, af1, acc[1][0], 0, 0, 0); \
            acc[1][1] = __builtin_amdgcn_mfma_f32_16x16x32_bf16(K11, af1, acc[1][1], 0, 0, 0); \
            acc[1][2] = __builtin_amdgcn_mfma_f32_16x16x32_bf16(K12, af1, acc[1][2], 0, 0, 0); \
            acc[1][3] = __builtin_amdgcn_mfma_f32_16x16x32_bf16(K13, af1, acc[1][3], 0, 0, 0); \
        }                                                                        \
    }

#define SB __builtin_amdgcn_sched_barrier(0);

    STAGE(0, 0);
    LOADB0(0, Ba0, Ba1, Ba2, Ba3);
    __syncthreads();

    LOADB1(0); SB; LOADB0(1, Bb0, Bb1, Bb2, Bb3); STAGE(1, 1);
    COMP(0, Ba0, Ba1, Ba2, Ba3); __syncthreads();

    LOADB1(1); SB; LOADB0(2, Ba0, Ba1, Ba2, Ba3); STAGE(2, 0);
    COMP(1, Bb0, Bb1, Bb2, Bb3); __syncthreads();

    LOADB1(2); SB; LOADB0(3, Bb0, Bb1, Bb2, Bb3); STAGE(3, 1);
    COMP(0, Ba0, Ba1, Ba2, Ba3); __syncthreads();

    LOADB1(3); SB; LOADB0(4, Ba0, Ba1, Ba2, Ba3); STAGE(4, 0);
    COMP(1, Bb0, Bb1, Bb2, Bb3); __syncthreads();

    LOADB1(4); SB; LOADB0(5, Bb0, Bb1, Bb2, Bb3); STAGE(5, 1);
    COMP(0, Ba0, Ba1, Ba2, Ba3); __syncthreads();

    LOADB1(5); SB; LOADB0(6, Ba0, Ba1, Ba2, Ba3); STAGE(6, 0);
    COMP(1, Bb0, Bb1, Bb2, Bb3); __syncthreads();

    LOADB1(6); SB; LOADB0(7, Bb0, Bb1, Bb2, Bb3); STAGE(7, 1);
    COMP(0, Ba0, Ba1, Ba2, Ba3); __syncthreads();

    LOADB1(7); SB;
    COMP(1, Bb0, Bb1, Bb2, Bb3);

#undef COMP

    const int cm  = lane & 15;
    const int cn0 = (lane >> 4) * 4;
#pragma unroll
    for (int mf = 0; mf < 2; ++mf) {
        const int grow = block_row + wm * 32 + mf * 16 + cm;
        if (grow < M) {
            unsigned short* zr = zb + (size_t)grow * OUT_DIM + wn * 64 + cn0;
#pragma unroll
            for (int nf = 0; nf < 4; ++nf) {
                uint2 u;
                u.x = pack2f(acc[mf][nf][0], acc[mf][nf][1]);
                u.y = pack2f(acc[mf][nf][2], acc[mf][nf][3]);
                *(uint2*)(zr + nf * 16) = u;
            }
        }
    }
#undef LOADB0
#undef LOADB1
#undef STAGE
#undef SB
}

// ---------------------------------------------------------------------------
// DIAGNOSTIC PROBE (rule #17): identical grid/LDS/barriers/DMA/B-loads as
// gemm_mfma, consumption (ds_read/cvt/MFMA/epilogue) removed. B regs kept
// live via asm sinks; gload_lds is side-effecting (can't be DCE'd). Writes
// nothing. Its duration = total_delta vs round 15 -> isolates memory-side
// cost of the schedule.
// ---------------------------------------------------------------------------
__global__ __launch_bounds__(256, 4) void stage_probe(const float* __restrict__ x,
                                                      const unsigned short* __restrict__ wt2,
                                                      int M) {
    __shared__ float sA[2][BM * BK];
    char* const pAb = (char*)sA;

    const int tid  = threadIdx.x;
    const int lane = tid & 63;
    const int wid  = tid >> 6;
    const int wn   = wid & 1;
    const int block_row = blockIdx.x * BM;

    const int fr  = lane & 15;
    const int fk4 = lane >> 4;

    const int s_row = lane >> 4;
    const int s_cb  = (lane & 15) * 16;

    const unsigned short* pb = wt2 + fk4 * 1024 + (wn * 64 + fr) * 8;

    bf16x8 Ba0, Ba1, Ba2, Ba3;
    bf16x8 K10, K11, K12, K13;

#define LOADB0(T)                                         \
    Ba0 = *(const bf16x8*)(pb + (T) * 8192 + 0);          \
    Ba1 = *(const bf16x8*)(pb + (T) * 8192 + 128);        \
    Ba2 = *(const bf16x8*)(pb + (T) * 8192 + 256);        \
    Ba3 = *(const bf16x8*)(pb + (T) * 8192 + 384);

#define LOADB1(T)                                         \
    K10 = *(const bf16x8*)(pb + (T) * 8192 + 4096 + 0);   \
    K11 = *(const bf16x8*)(pb + (T) * 8192 + 4096 + 128); \
    K12 = *(const bf16x8*)(pb + (T) * 8192 + 4096 + 256); \
    K13 = *(const bf16x8*)(pb + (T) * 8192 + 4096 + 384);

#define STAGE(T, BUF)                                                            \
    {                                                                            \
        _Pragma("unroll") for (int i = 0; i < 4; ++i) {                          \
            const int rr = (wid * 4 + i) * 4 + s_row;                            \
            int grow = block_row + rr;                                           \
            grow = (grow < M) ? grow : (M - 1);                                  \
            const char* src = (const char*)x + (size_t)grow * 2048 +             \
                              (T) * 256 + (s_cb ^ ((rr & 7) << 5));              \
            gload_lds16(src, pAb + (BUF) * 16384 + (wid * 4 + i) * 1024);        \
        }                                                                        \
    }

    // sink: keep B registers live without any stores
#define SINK                                                                     \
    asm volatile("" :: "v"(Ba0), "v"(Ba1), "v"(Ba2), "v"(Ba3),                   \
                       "v"(K10), "v"(K11), "v"(K12), "v"(K13));

#define SB __builtin_amdgcn_sched_barrier(0);

    STAGE(0, 0);
    LOADB0(0);
    __syncthreads();

    LOADB1(0); SB; LOADB0(1); STAGE(1, 1); SINK; __syncthreads();
    LOADB1(1); SB; LOADB0(2); STAGE(2, 0); SINK; __syncthreads();
    LOADB1(2); SB; LOADB0(3); STAGE(3, 1); SINK; __syncthreads();
    LOADB1(3); SB; LOADB0(4); STAGE(4, 0); SINK; __syncthreads();
    LOADB1(4); SB; LOADB0(5); STAGE(5, 1); SINK; __syncthreads();
    LOADB1(5); SB; LOADB0(6); STAGE(6, 0); SINK; __syncthreads();
    LOADB1(6); SB; LOADB0(7); STAGE(7, 1); SINK; __syncthreads();
    LOADB1(7); SB; SINK;

#undef LOADB0
#undef LOADB1
#undef STAGE
#undef SINK
#undef SB
}

// ---------------------------------------------------------------------------
// Decode: out[e] = sigmoid( sum_k z[a_e,k]*z[b_e,k]*w3[k] ), z in bf16.
// ---------------------------------------------------------------------------
__device__ inline float dotw3(const uint4& ua, const uint4& ub, const f32x2* w3v) {
    const unsigned pa[4] = {ua.x, ua.y, ua.z, ua.w};
    const unsigned pb[4] = {ub.x, ub.y, ub.z, ub.w};
    f32x2 vv = (f32x2){0.f, 0.f};
#pragma unroll
    for (int i = 0; i < 4; ++i) {
        f32x2 A = (f32x2){__uint_as_float(pa[i] << 16),
                          __uint_as_float(pa[i] & 0xFFFF0000u)};
        f32x2 B = (f32x2){__uint_as_float(pb[i] << 16),
                          __uint_as_float(pb[i] & 0xFFFF0000u)};
        vv += (A * B) * w3v[i];
    }
    return vv.x + vv.y;
}

__global__ __launch_bounds__(256) void decode_kernel(const unsigned short* __restrict__ zb,
                                                     const int* __restrict__ e1,
                                                     const int* __restrict__ e2,
                                                     const float* __restrict__ w3,
                                                     float* __restrict__ out,
                                                     int E1, int E2) {
    const int tid  = threadIdx.x;
    const int lane = tid & 63;
    const int sub  = lane & 15;
    const int sg   = lane >> 4;
    const int Etot = E1 + E2;
    const int nq   = (Etot + 3) >> 2;

    f32x2 w3v[4];
    {
        const float4 wlo = *(const float4*)(w3 + sub * 8);
        const float4 whi = *(const float4*)(w3 + sub * 8 + 4);
        w3v[0] = (f32x2){wlo.x, wlo.y};
        w3v[1] = (f32x2){wlo.z, wlo.w};
        w3v[2] = (f32x2){whi.x, whi.y};
        w3v[3] = (f32x2){whi.z, whi.w};
    }

    const int wave = blockIdx.x * 4 + (tid >> 6);
    const int S    = gridDim.x * 4;

    for (int q = wave; q < nq; q += 2 * S) {
        const int q2    = q + S;
        const bool has2 = (q2 < nq);

        const int e_a = q * 4 + sg;
        const int e_b = has2 ? (q2 * 4 + sg) : e_a;
        const int ca  = min(e_a, Etot - 1);
        const int cb  = min(e_b, Etot - 1);

        const int2 ia = (ca < E1) ? ((const int2*)e1)[ca] : ((const int2*)e2)[ca - E1];
        const int2 ib = (cb < E1) ? ((const int2*)e1)[cb] : ((const int2*)e2)[cb - E1];

        const uint4 a1 = *(const uint4*)(zb + (size_t)ia.x * OUT_DIM + sub * 8);
        const uint4 b1 = *(const uint4*)(zb + (size_t)ia.y * OUT_DIM + sub * 8);
        const uint4 a2 = *(const uint4*)(zb + (size_t)ib.x * OUT_DIM + sub * 8);
        const uint4 b2 = *(const uint4*)(zb + (size_t)ib.y * OUT_DIM + sub * 8);

        float v1 = dotw3(a1, b1, w3v);
        float v2 = dotw3(a2, b2, w3v);

        v1 += __shfl_xor(v1, 8);  v2 += __shfl_xor(v2, 8);
        v1 += __shfl_xor(v1, 4);  v2 += __shfl_xor(v2, 4);
        v1 += __shfl_xor(v1, 2);  v2 += __shfl_xor(v2, 2);
        v1 += __shfl_xor(v1, 1);  v2 += __shfl_xor(v2, 1);

        if (sub == 0) {
            if (e_a < Etot) out[e_a] = 1.f / (1.f + __expf(-v1));
            if (has2 && e_b < Etot) out[e_b] = 1.f / (1.f + __expf(-v2));
        }
    }
}

extern "C" void kernel_launch(void* const* d_in, const int* in_sizes, int n_in,
                              void* d_out, int out_size, void* d_ws, size_t ws_size,
                              hipStream_t stream) {
    const float* x  = (const float*)d_in[0];
    const int*   e1 = (const int*)d_in[1];
    const int*   e2 = (const int*)d_in[2];
    const float* w  = (const float*)d_in[3];
    const float* w3 = (const float*)d_in[4];

    float* out = (float*)d_out;

    const int M  = in_sizes[0] / IN_DIM;  // 100000
    const int E1 = in_sizes[1] / 2;       // 300000
    const int E2 = in_sizes[2] / 2;       // 300000

    unsigned short* zbuf = (unsigned short*)d_ws;
    unsigned short* wt2  = zbuf + (size_t)M * OUT_DIM;

    wt2_kernel<<<(IN_DIM * OUT_DIM) / 256, 256, 0, stream>>>(w, wt2);
    gemm_mfma<<<(M + BM - 1) / BM, 256, 0, stream>>>(x, wt2, zbuf, M);
    decode_kernel<<<2048, 256, 0, stream>>>(zbuf, e1, e2, w3, out, E1, E2);
    // diagnostic: staging-only replica of gemm_mfma (no output; timed via total)
    stage_probe<<<(M + BM - 1) / BM, 256, 0, stream>>>(x, wt2, M);
}

// Round 17
// 102.874 us; speedup vs baseline: 1.1679x; 1.1679x over previous
//
#include <hip/hip_runtime.h>
#include <math.h>

#define IN_DIM 512
#define OUT_DIM 128
#define BM 64

typedef __attribute__((ext_vector_type(8))) __bf16 bf16x8;
typedef __attribute__((ext_vector_type(2))) __bf16 bf16x2;
typedef __attribute__((ext_vector_type(4))) float f32x4;
typedef __attribute__((ext_vector_type(2))) float f32x2;

// Manual RNE fp32->bf16 (bit ops) — r5-proven codegen for epilogue/prep.
__device__ inline unsigned short f2bf(float f) {
    unsigned u = __float_as_uint(f);
    u += 0x7FFFu + ((u >> 16) & 1u);  // round-to-nearest-even
    return (unsigned short)(u >> 16);
}
__device__ inline unsigned pack2f(float a, float b) {
    return (unsigned)f2bf(a) | ((unsigned)f2bf(b) << 16);
}

// In-register fp32x8 -> bf16x8 via native paired casts, consumed immediately.
__device__ inline bf16x8 cvt8(const f32x4& lo, const f32x4& hi) {
    bf16x2 p0 = {(__bf16)lo.x, (__bf16)lo.y};
    bf16x2 p1 = {(__bf16)lo.z, (__bf16)lo.w};
    bf16x2 p2 = {(__bf16)hi.x, (__bf16)hi.y};
    bf16x2 p3 = {(__bf16)hi.z, (__bf16)hi.w};
    uint4 u = {__builtin_bit_cast(unsigned, p0), __builtin_bit_cast(unsigned, p1),
               __builtin_bit_cast(unsigned, p2), __builtin_bit_cast(unsigned, p3)};
    return __builtin_bit_cast(bf16x8, u);
}

// async global->LDS, 16B per lane (dest = wave-uniform base + lane*16)
__device__ inline void gload_lds16(const void* g, void* l) {
    __builtin_amdgcn_global_load_lds(
        (const __attribute__((address_space(1))) void*)g,
        (__attribute__((address_space(3))) void*)l, 16, 0, 0);
}

// w [512][128] f32 -> wt2 k-interleaved bf16: wt2[(k>>3)*128 + n][k&7]
__global__ void wt2_kernel(const float* __restrict__ w, unsigned short* __restrict__ wt2) {
    int idx = blockIdx.x * 256 + threadIdx.x;  // 65536 total
    int k = idx >> 7;
    int n = idx & 127;
    wt2[(((k >> 3) * 128) + n) * 8 + (k & 7)] = f2bf(w[idx]);
}

// ---------------------------------------------------------------------------
// z_bf[M,128](bf16) = x[M,512] @ w[512,128] via bf16 MFMA, fp32 accumulate.
// MAX-TLP + WAVE-PRIVATE, ZERO barriers. Diagnostic r16 showed staging alone
// runs at the BW envelope (31 µs) while the full kernel ran 74 µs at only
// 4 waves/SIMD — the dependent ds_read->cvt->MFMA chain was uncovered.
// This variant: wave = 16x64 out (acc 16 VGPR), BK=32, wave-private 2x2 KB
// LDS double-buffer, per-tile FIFO-correct order
//   LOADB(t) -> STAGE(t+1) -> vmcnt(2) -> ds_read+cvt+4 MFMA
// (vmcnt(2) retires DMA(t)+B(t), leaves DMA(t+1) in flight). No barriers:
// race-free because each wave owns its LDS slice. __launch_bounds__(512,8)
// caps VGPR at 64 -> 8 waves/SIMD, 32 waves/CU — 2x all prior rounds.
// Swapped-operand MFMA -> packed uint2 epilogue (r13-validated).
// ---------------------------------------------------------------------------
__global__ __launch_bounds__(512, 8) void gemm_mfma(const float* __restrict__ x,
                                                    const unsigned short* __restrict__ wt2,
                                                    unsigned short* __restrict__ zb,
                                                    int M) {
    __shared__ float sA[8][1024];  // 8 waves x (2 bufs x 2 KB) = 32 KB
    char* const pAb = (char*)sA;

    const int tid  = threadIdx.x;
    const int lane = tid & 63;
    const int wid  = tid >> 6;  // 0..7
    const int wm   = wid >> 1;  // 0..3 : 16-row slice
    const int wn   = wid & 1;   // 0..1 : 64-col half
    const int block_row = blockIdx.x * BM;

    const int fr  = lane & 15;  // fragment row (A=m) / col (B=n)
    const int fk4 = lane >> 4;  // k-octet group 0..3

    f32x4 acc[4];
#pragma unroll
    for (int j = 0; j < 4; ++j) acc[j] = (f32x4){0.f, 0.f, 0.f, 0.f};

    // staging map (per wave, 16 rows x 32 k fp32 = 2 KB = 2 chunks of 1 KB).
    // Chunk j: rows 8j..8j+7; lane: row 8j+(lane>>3), 16B-slot lane&7.
    // Source col-byte inverse-swizzled by ((lane>>3)&7)<<4 (both-sides rule).
    const int s_cb = ((lane & 7) * 16) ^ ((lane >> 3) << 4);
    int r0 = block_row + wm * 16 + (lane >> 3);     r0 = (r0 < M) ? r0 : (M - 1);
    int r1 = r0 + 8;                                 r1 = (r1 < M) ? r1 : (M - 1);
    const char* sb0 = (const char*)x + (size_t)r0 * 2048 + s_cb;
    const char* sb1 = (const char*)x + (size_t)r1 * 2048 + s_cb;
    char* const wbase = pAb + wid * 4096;  // wave-private 4 KB (2 x 2 KB)

    // fragment-read map (logical row fr, swizzled column)
    const int swz = (fr & 7) << 4;
    const int cb0 = (fk4 * 32) ^ swz;
    const int cb1 = (fk4 * 32 + 16) ^ swz;
    const int rb  = fr * 128;  // row byte (128 B per row = 32 fp32)

    // B per-lane base in wt2 (element units); tile t -> + t*4096
    const unsigned short* pb = wt2 + fk4 * 1024 + (wn * 64 + fr) * 8;

    bf16x8 bv0, bv1, bv2, bv3;

#define LOADB(BYTEOFF)                                              \
    bv0 = *(const bf16x8*)(pb + (BYTEOFF) / 2 + 0);                 \
    bv1 = *(const bf16x8*)(pb + (BYTEOFF) / 2 + 128);               \
    bv2 = *(const bf16x8*)(pb + (BYTEOFF) / 2 + 256);               \
    bv3 = *(const bf16x8*)(pb + (BYTEOFF) / 2 + 384);

#define STAGE(T, BUF)                                               \
    gload_lds16(sb0 + (T) * 128, wbase + (BUF) * 2048);             \
    gload_lds16(sb1 + (T) * 128, wbase + (BUF) * 2048 + 1024);

#define WAITN(N)                                                    \
    asm volatile("s_waitcnt vmcnt(" #N ")" ::: "memory");           \
    __builtin_amdgcn_sched_barrier(0);

#define COMP(BUF)                                                                \
    {                                                                            \
        const char* pT = wbase + (BUF) * 2048;                                   \
        f32x4 lo = *(const f32x4*)(pT + rb + cb0);                               \
        f32x4 hi = *(const f32x4*)(pT + rb + cb1);                               \
        bf16x8 af = cvt8(lo, hi);                                                \
        acc[0] = __builtin_amdgcn_mfma_f32_16x16x32_bf16(bv0, af, acc[0], 0, 0, 0); \
        acc[1] = __builtin_amdgcn_mfma_f32_16x16x32_bf16(bv1, af, acc[1], 0, 0, 0); \
        acc[2] = __builtin_amdgcn_mfma_f32_16x16x32_bf16(bv2, af, acc[2], 0, 0, 0); \
        acc[3] = __builtin_amdgcn_mfma_f32_16x16x32_bf16(bv3, af, acc[3], 0, 0, 0); \
    }

    // prologue: tile 0 staged into buf0
    STAGE(0, 0);

#pragma unroll
    for (int p = 0; p < 8; ++p) {
        // tile e = 2p  (buf0)
        LOADB(p * 16384);            // B(2p): oldest after DMA(2p)
        STAGE(2 * p + 1, 1);         // DMA(2p+1): youngest
        WAITN(2);                    // retire DMA(2p)+B(2p), keep DMA(2p+1)
        COMP(0);

        // tile o = 2p+1  (buf1)
        LOADB(p * 16384 + 8192);     // B(2p+1)
        if (p < 7) {
            STAGE(2 * p + 2, 0);     // DMA(2p+2)
            WAITN(2);
        } else {
            WAITN(0);
        }
        COMP(1);
    }

#undef LOADB
#undef STAGE
#undef WAITN
#undef COMP

    // Swapped C/D layout: col=lane&15 -> m, row=(lane>>4)*4+reg -> n.
    const int cm  = lane & 15;
    const int cn0 = (lane >> 4) * 4;
    const int grow = block_row + wm * 16 + cm;
    if (grow < M) {
        unsigned short* zr = zb + (size_t)grow * OUT_DIM + wn * 64 + cn0;
#pragma unroll
        for (int nf = 0; nf < 4; ++nf) {
            uint2 u;
            u.x = pack2f(acc[nf][0], acc[nf][1]);
            u.y = pack2f(acc[nf][2], acc[nf][3]);
            *(uint2*)(zr + nf * 16) = u;
        }
    }
}

// ---------------------------------------------------------------------------
// Decode: out[e] = sigmoid( sum_k z[a_e,k]*z[b_e,k]*w3[k] ), z in bf16.
// 16 lanes per edge, 4 edges/wave, grid-stride UNROLLED x2 (2x MLP).
// ---------------------------------------------------------------------------
__device__ inline float dotw3(const uint4& ua, const uint4& ub, const f32x2* w3v) {
    const unsigned pa[4] = {ua.x, ua.y, ua.z, ua.w};
    const unsigned pb[4] = {ub.x, ub.y, ub.z, ub.w};
    f32x2 vv = (f32x2){0.f, 0.f};
#pragma unroll
    for (int i = 0; i < 4; ++i) {
        f32x2 A = (f32x2){__uint_as_float(pa[i] << 16),
                          __uint_as_float(pa[i] & 0xFFFF0000u)};
        f32x2 B = (f32x2){__uint_as_float(pb[i] << 16),
                          __uint_as_float(pb[i] & 0xFFFF0000u)};
        vv += (A * B) * w3v[i];  // v_pk_mul_f32 + v_pk_fma_f32
    }
    return vv.x + vv.y;
}

__global__ __launch_bounds__(256) void decode_kernel(const unsigned short* __restrict__ zb,
                                                     const int* __restrict__ e1,
                                                     const int* __restrict__ e2,
                                                     const float* __restrict__ w3,
                                                     float* __restrict__ out,
                                                     int E1, int E2) {
    const int tid  = threadIdx.x;
    const int lane = tid & 63;
    const int sub  = lane & 15;
    const int sg   = lane >> 4;
    const int Etot = E1 + E2;
    const int nq   = (Etot + 3) >> 2;

    f32x2 w3v[4];
    {
        const float4 wlo = *(const float4*)(w3 + sub * 8);
        const float4 whi = *(const float4*)(w3 + sub * 8 + 4);
        w3v[0] = (f32x2){wlo.x, wlo.y};
        w3v[1] = (f32x2){wlo.z, wlo.w};
        w3v[2] = (f32x2){whi.x, whi.y};
        w3v[3] = (f32x2){whi.z, whi.w};
    }

    const int wave = blockIdx.x * 4 + (tid >> 6);
    const int S    = gridDim.x * 4;

    for (int q = wave; q < nq; q += 2 * S) {
        const int q2    = q + S;
        const bool has2 = (q2 < nq);

        const int e_a = q * 4 + sg;
        const int e_b = has2 ? (q2 * 4 + sg) : e_a;
        const int ca  = min(e_a, Etot - 1);
        const int cb  = min(e_b, Etot - 1);

        const int2 ia = (ca < E1) ? ((const int2*)e1)[ca] : ((const int2*)e2)[ca - E1];
        const int2 ib = (cb < E1) ? ((const int2*)e1)[cb] : ((const int2*)e2)[cb - E1];

        const uint4 a1 = *(const uint4*)(zb + (size_t)ia.x * OUT_DIM + sub * 8);
        const uint4 b1 = *(const uint4*)(zb + (size_t)ia.y * OUT_DIM + sub * 8);
        const uint4 a2 = *(const uint4*)(zb + (size_t)ib.x * OUT_DIM + sub * 8);
        const uint4 b2 = *(const uint4*)(zb + (size_t)ib.y * OUT_DIM + sub * 8);

        float v1 = dotw3(a1, b1, w3v);
        float v2 = dotw3(a2, b2, w3v);

        v1 += __shfl_xor(v1, 8);  v2 += __shfl_xor(v2, 8);
        v1 += __shfl_xor(v1, 4);  v2 += __shfl_xor(v2, 4);
        v1 += __shfl_xor(v1, 2);  v2 += __shfl_xor(v2, 2);
        v1 += __shfl_xor(v1, 1);  v2 += __shfl_xor(v2, 1);

        if (sub == 0) {
            if (e_a < Etot) out[e_a] = 1.f / (1.f + __expf(-v1));
            if (has2 && e_b < Etot) out[e_b] = 1.f / (1.f + __expf(-v2));
        }
    }
}

extern "C" void kernel_launch(void* const* d_in, const int* in_sizes, int n_in,
                              void* d_out, int out_size, void* d_ws, size_t ws_size,
                              hipStream_t stream) {
    const float* x  = (const float*)d_in[0];
    const int*   e1 = (const int*)d_in[1];
    const int*   e2 = (const int*)d_in[2];
    const float* w  = (const float*)d_in[3];
    const float* w3 = (const float*)d_in[4];

    float* out = (float*)d_out;

    const int M  = in_sizes[0] / IN_DIM;  // 100000
    const int E1 = in_sizes[1] / 2;       // 300000
    const int E2 = in_sizes[2] / 2;       // 300000

    // workspace: z_bf [M,128] bf16 (25.6 MB), then wt2 [512x128] bf16 (128 KB)
    unsigned short* zbuf = (unsigned short*)d_ws;
    unsigned short* wt2  = zbuf + (size_t)M * OUT_DIM;

    wt2_kernel<<<(IN_DIM * OUT_DIM) / 256, 256, 0, stream>>>(w, wt2);
    gemm_mfma<<<(M + BM - 1) / BM, 512, 0, stream>>>(x, wt2, zbuf, M);
    decode_kernel<<<2048, 256, 0, stream>>>(zbuf, e1, e2, w3, out, E1, E2);
}

// Round 18
// 89.310 us; speedup vs baseline: 1.3453x; 1.1519x over previous
//
#include <hip/hip_runtime.h>
#include <math.h>

#define IN_DIM 512
#define OUT_DIM 128
#define BM 64
#define BK 32
#define NKT (IN_DIM / BK)  // 16

typedef __attribute__((ext_vector_type(8))) __bf16 bf16x8;
typedef __attribute__((ext_vector_type(2))) __bf16 bf16x2;
typedef __attribute__((ext_vector_type(4))) float f32x4;
typedef __attribute__((ext_vector_type(2))) float f32x2;

// Manual RNE fp32->bf16 (bit ops) — r5-proven codegen for epilogue/prep.
__device__ inline unsigned short f2bf(float f) {
    unsigned u = __float_as_uint(f);
    u += 0x7FFFu + ((u >> 16) & 1u);  // round-to-nearest-even
    return (unsigned short)(u >> 16);
}
__device__ inline unsigned pack2f(float a, float b) {
    return (unsigned)f2bf(a) | ((unsigned)f2bf(b) << 16);
}

// In-register fp32x8 -> bf16x8 via native paired casts, consumed immediately.
__device__ inline bf16x8 cvt8(const f32x4& lo, const f32x4& hi) {
    bf16x2 p0 = {(__bf16)lo.x, (__bf16)lo.y};
    bf16x2 p1 = {(__bf16)lo.z, (__bf16)lo.w};
    bf16x2 p2 = {(__bf16)hi.x, (__bf16)hi.y};
    bf16x2 p3 = {(__bf16)hi.z, (__bf16)hi.w};
    uint4 u = {__builtin_bit_cast(unsigned, p0), __builtin_bit_cast(unsigned, p1),
               __builtin_bit_cast(unsigned, p2), __builtin_bit_cast(unsigned, p3)};
    return __builtin_bit_cast(bf16x8, u);
}

// async global->LDS, 16B per lane (dest = wave-uniform base + lane*16)
__device__ inline void gload_lds16(const void* g, void* l) {
    __builtin_amdgcn_global_load_lds(
        (const __attribute__((address_space(1))) void*)g,
        (__attribute__((address_space(3))) void*)l, 16, 0, 0);
}

// w [512][128] f32 -> wt2 k-interleaved bf16: wt2[(k>>3)*128 + n][k&7]
__global__ void wt2_kernel(const float* __restrict__ w, unsigned short* __restrict__ wt2) {
    int idx = blockIdx.x * 256 + threadIdx.x;  // 65536 total
    int k = idx >> 7;
    int n = idx & 127;
    wt2[(((k >> 3) * 128) + n) * 8 + (k & 7)] = f2bf(w[idx]);
}

// ---------------------------------------------------------------------------
// z_bf[M,128](bf16) = x[M,512] @ w[512,128] via bf16 MFMA, fp32 accumulate.
// r10 champion structure at BK=32 for 6 blocks/CU (occupancy hypothesis,
// clean test): shared DMA-staged A (2 x 8 KB double buffer), in-phase B from
// L2-resident wt2, drain barrier per phase, 16 phases. Wave tile 32x64
// (same arithmetic intensity as champion; B-duplication stays 2x).
// acc 32 + transient regs ~= 75 VGPR -> __launch_bounds__(256,6) fits:
// 6 blocks/CU x 4 waves = 24 waves/CU = 1.5x champion's streams.
// Both-sides XOR swizzle on A (<=2-way LDS conflicts). Swapped-operand MFMA
// -> packed uint2 epilogue (r13-validated).
// ---------------------------------------------------------------------------
__global__ __launch_bounds__(256, 6) void gemm_mfma(const float* __restrict__ x,
                                                    const unsigned short* __restrict__ wt2,
                                                    unsigned short* __restrict__ zb,
                                                    int M) {
    __shared__ float sA[2][BM * BK];  // 2 x 8 KB fp32, col-swizzled
    char* const pAb = (char*)sA;

    const int tid  = threadIdx.x;
    const int lane = tid & 63;
    const int wid  = tid >> 6;
    const int wm   = wid >> 1;  // 0..1
    const int wn   = wid & 1;   // 0..1
    const int block_row = blockIdx.x * BM;

    const int fr  = lane & 15;  // fragment row (A=m) / col (B=n)
    const int fk4 = lane >> 4;  // k-octet group 0..3

    f32x4 acc[2][4];
#pragma unroll
    for (int i = 0; i < 2; ++i)
#pragma unroll
        for (int j = 0; j < 4; ++j) acc[i][j] = (f32x4){0.f, 0.f, 0.f, 0.f};

    // staging map: 8 chunks of 1 KB (8 rows x 32 fp32); wave wid handles
    // chunks 2*wid, 2*wid+1. Lane: row-in-chunk lane>>3, 16B-slot lane&7.
    // Source col-byte inverse-swizzled by ((lane>>3)&7)<<4 (both-sides rule).
    const int s_cb = ((lane & 7) * 16) ^ ((lane >> 3) << 4);
    const char* sb0;  // chunk 2*wid   source base (row part)
    const char* sb1;  // chunk 2*wid+1
    {
        int r0 = block_row + (wid * 2 + 0) * 8 + (lane >> 3); r0 = (r0 < M) ? r0 : (M - 1);
        int r1 = block_row + (wid * 2 + 1) * 8 + (lane >> 3); r1 = (r1 < M) ? r1 : (M - 1);
        sb0 = (const char*)x + (size_t)r0 * 2048 + s_cb;
        sb1 = (const char*)x + (size_t)r1 * 2048 + s_cb;
    }
    const int d0 = (wid * 2 + 0) * 1024;  // LDS chunk dests
    const int d1 = (wid * 2 + 1) * 1024;

    // fragment-read map (logical row, swizzled column); row stride 128 B
    const int rowa0 = wm * 32 + fr;
    const int rowa1 = rowa0 + 16;
    const int swz   = (fr & 7) << 4;
    const int c0    = (fk4 * 32) ^ swz;
    const int c1    = (fk4 * 32 + 16) ^ swz;

    // B per-lane base in wt2 (element units); tile t -> + t*4096
    const unsigned short* pb = wt2 + fk4 * 1024 + (wn * 64 + fr) * 8;

#define STAGE(T, BUF)                                               \
    gload_lds16(sb0 + (T) * 128, pAb + (BUF) * 8192 + d0);          \
    gload_lds16(sb1 + (T) * 128, pAb + (BUF) * 8192 + d1);

#define COMP(T, BUF)                                                             \
    {                                                                            \
        const char* pT = pAb + (BUF) * 8192;                                     \
        f32x4 lo0 = *(const f32x4*)(pT + rowa0 * 128 + c0);                      \
        f32x4 hi0 = *(const f32x4*)(pT + rowa0 * 128 + c1);                      \
        f32x4 lo1 = *(const f32x4*)(pT + rowa1 * 128 + c0);                      \
        f32x4 hi1 = *(const f32x4*)(pT + rowa1 * 128 + c1);                      \
        bf16x8 af0 = cvt8(lo0, hi0);                                             \
        bf16x8 af1 = cvt8(lo1, hi1);                                             \
        bf16x8 bv0 = *(const bf16x8*)(pb + (T) * 4096 + 0);                      \
        bf16x8 bv1 = *(const bf16x8*)(pb + (T) * 4096 + 128);                    \
        bf16x8 bv2 = *(const bf16x8*)(pb + (T) * 4096 + 256);                    \
        bf16x8 bv3 = *(const bf16x8*)(pb + (T) * 4096 + 384);                    \
        acc[0][0] = __builtin_amdgcn_mfma_f32_16x16x32_bf16(bv0, af0, acc[0][0], 0, 0, 0); \
        acc[0][1] = __builtin_amdgcn_mfma_f32_16x16x32_bf16(bv1, af0, acc[0][1], 0, 0, 0); \
        acc[0][2] = __builtin_amdgcn_mfma_f32_16x16x32_bf16(bv2, af0, acc[0][2], 0, 0, 0); \
        acc[0][3] = __builtin_amdgcn_mfma_f32_16x16x32_bf16(bv3, af0, acc[0][3], 0, 0, 0); \
        acc[1][0] = __builtin_amdgcn_mfma_f32_16x16x32_bf16(bv0, af1, acc[1][0], 0, 0, 0); \
        acc[1][1] = __builtin_amdgcn_mfma_f32_16x16x32_bf16(bv1, af1, acc[1][1], 0, 0, 0); \
        acc[1][2] = __builtin_amdgcn_mfma_f32_16x16x32_bf16(bv2, af1, acc[1][2], 0, 0, 0); \
        acc[1][3] = __builtin_amdgcn_mfma_f32_16x16x32_bf16(bv3, af1, acc[1][3], 0, 0, 0); \
    }

    // prologue: stage tile 0
    STAGE(0, 0);
    __syncthreads();

#pragma unroll
    for (int t = 0; t < NKT; ++t) {
        if (t + 1 < NKT) STAGE(t + 1, (t + 1) & 1);
        COMP(t, t & 1);
        __syncthreads();  // drains STAGE(t+1) DMA + gates buffer reuse
    }

#undef STAGE
#undef COMP

    // Swapped C/D layout: col=lane&15 -> m, row=(lane>>4)*4+reg -> n.
    const int cm  = lane & 15;
    const int cn0 = (lane >> 4) * 4;
#pragma unroll
    for (int mf = 0; mf < 2; ++mf) {
        const int grow = block_row + wm * 32 + mf * 16 + cm;
        if (grow < M) {
            unsigned short* zr = zb + (size_t)grow * OUT_DIM + wn * 64 + cn0;
#pragma unroll
            for (int nf = 0; nf < 4; ++nf) {
                uint2 u;
                u.x = pack2f(acc[mf][nf][0], acc[mf][nf][1]);
                u.y = pack2f(acc[mf][nf][2], acc[mf][nf][3]);
                *(uint2*)(zr + nf * 16) = u;
            }
        }
    }
}

// ---------------------------------------------------------------------------
// Decode: out[e] = sigmoid( sum_k z[a_e,k]*z[b_e,k]*w3[k] ), z in bf16.
// 16 lanes per edge, 4 edges/wave, grid-stride UNROLLED x2 (2x MLP).
// ---------------------------------------------------------------------------
__device__ inline float dotw3(const uint4& ua, const uint4& ub, const f32x2* w3v) {
    const unsigned pa[4] = {ua.x, ua.y, ua.z, ua.w};
    const unsigned pb[4] = {ub.x, ub.y, ub.z, ub.w};
    f32x2 vv = (f32x2){0.f, 0.f};
#pragma unroll
    for (int i = 0; i < 4; ++i) {
        f32x2 A = (f32x2){__uint_as_float(pa[i] << 16),
                          __uint_as_float(pa[i] & 0xFFFF0000u)};
        f32x2 B = (f32x2){__uint_as_float(pb[i] << 16),
                          __uint_as_float(pb[i] & 0xFFFF0000u)};
        vv += (A * B) * w3v[i];  // v_pk_mul_f32 + v_pk_fma_f32
    }
    return vv.x + vv.y;
}

__global__ __launch_bounds__(256) void decode_kernel(const unsigned short* __restrict__ zb,
                                                     const int* __restrict__ e1,
                                                     const int* __restrict__ e2,
                                                     const float* __restrict__ w3,
                                                     float* __restrict__ out,
                                                     int E1, int E2) {
    const int tid  = threadIdx.x;
    const int lane = tid & 63;
    const int sub  = lane & 15;
    const int sg   = lane >> 4;
    const int Etot = E1 + E2;
    const int nq   = (Etot + 3) >> 2;

    f32x2 w3v[4];
    {
        const float4 wlo = *(const float4*)(w3 + sub * 8);
        const float4 whi = *(const float4*)(w3 + sub * 8 + 4);
        w3v[0] = (f32x2){wlo.x, wlo.y};
        w3v[1] = (f32x2){wlo.z, wlo.w};
        w3v[2] = (f32x2){whi.x, whi.y};
        w3v[3] = (f32x2){whi.z, whi.w};
    }

    const int wave = blockIdx.x * 4 + (tid >> 6);
    const int S    = gridDim.x * 4;

    for (int q = wave; q < nq; q += 2 * S) {
        const int q2    = q + S;
        const bool has2 = (q2 < nq);

        const int e_a = q * 4 + sg;
        const int e_b = has2 ? (q2 * 4 + sg) : e_a;
        const int ca  = min(e_a, Etot - 1);
        const int cb  = min(e_b, Etot - 1);

        const int2 ia = (ca < E1) ? ((const int2*)e1)[ca] : ((const int2*)e2)[ca - E1];
        const int2 ib = (cb < E1) ? ((const int2*)e1)[cb] : ((const int2*)e2)[cb - E1];

        const uint4 a1 = *(const uint4*)(zb + (size_t)ia.x * OUT_DIM + sub * 8);
        const uint4 b1 = *(const uint4*)(zb + (size_t)ia.y * OUT_DIM + sub * 8);
        const uint4 a2 = *(const uint4*)(zb + (size_t)ib.x * OUT_DIM + sub * 8);
        const uint4 b2 = *(const uint4*)(zb + (size_t)ib.y * OUT_DIM + sub * 8);

        float v1 = dotw3(a1, b1, w3v);
        float v2 = dotw3(a2, b2, w3v);

        v1 += __shfl_xor(v1, 8);  v2 += __shfl_xor(v2, 8);
        v1 += __shfl_xor(v1, 4);  v2 += __shfl_xor(v2, 4);
        v1 += __shfl_xor(v1, 2);  v2 += __shfl_xor(v2, 2);
        v1 += __shfl_xor(v1, 1);  v2 += __shfl_xor(v2, 1);

        if (sub == 0) {
            if (e_a < Etot) out[e_a] = 1.f / (1.f + __expf(-v1));
            if (has2 && e_b < Etot) out[e_b] = 1.f / (1.f + __expf(-v2));
        }
    }
}

extern "C" void kernel_launch(void* const* d_in, const int* in_sizes, int n_in,
                              void* d_out, int out_size, void* d_ws, size_t ws_size,
                              hipStream_t stream) {
    const float* x  = (const float*)d_in[0];
    const int*   e1 = (const int*)d_in[1];
    const int*   e2 = (const int*)d_in[2];
    const float* w  = (const float*)d_in[3];
    const float* w3 = (const float*)d_in[4];

    float* out = (float*)d_out;

    const int M  = in_sizes[0] / IN_DIM;  // 100000
    const int E1 = in_sizes[1] / 2;       // 300000
    const int E2 = in_sizes[2] / 2;       // 300000

    // workspace: z_bf [M,128] bf16 (25.6 MB), then wt2 [512x128] bf16 (128 KB)
    unsigned short* zbuf = (unsigned short*)d_ws;
    unsigned short* wt2  = zbuf + (size_t)M * OUT_DIM;

    wt2_kernel<<<(IN_DIM * OUT_DIM) / 256, 256, 0, stream>>>(w, wt2);
    gemm_mfma<<<(M + BM - 1) / BM, 256, 0, stream>>>(x, wt2, zbuf, M);
    decode_kernel<<<2048, 256, 0, stream>>>(zbuf, e1, e2, w3, out, E1, E2);
}